// Round 1
// baseline (961.491 us; speedup 1.0000x reference)
//
#include <hip/hip_runtime.h>
#include <math.h>

#define DIM 512
#define HEADS 8
#define QL 225
#define VS 196
#define BATCH 4
#define EPS_BN 1e-5f

// ---------------- block reduction helpers (block = 256 threads) ----------------
__device__ __forceinline__ float blockReduceMax(float v, float* red, int tid) {
    red[tid] = v; __syncthreads();
    for (int s = 128; s > 0; s >>= 1) {
        if (tid < s) red[tid] = fmaxf(red[tid], red[tid + s]);
        __syncthreads();
    }
    float r = red[0]; __syncthreads();
    return r;
}
__device__ __forceinline__ float blockReduceSum(float v, float* red, int tid) {
    red[tid] = v; __syncthreads();
    for (int s = 128; s > 0; s >>= 1) {
        if (tid < s) red[tid] += red[tid + s];
        __syncthreads();
    }
    float r = red[0]; __syncthreads();
    return r;
}

// ---------------- generic fp32 GEMM: Out[m,n] = scale*sum_k A[row(m),k]*W[n,k] (+bias)(relu)(+Add) ----
// A rows mapped: b = m / aBatchRows, r = m % aBatchRows, row ptr = A + b*aBatchStride + aRowOff + r*K
__global__ __launch_bounds__(256) void gemm_xwt(
    const float* __restrict__ A, int aBatchRows, long aBatchStride, long aRowOff,
    const float* __restrict__ W, const float* __restrict__ bias,
    const float* __restrict__ Add, int addBatchRows, long addBatchStride, long addRowOff,
    float* __restrict__ Out, int M, int N, int K, float scale, int reluFlag) {
    __shared__ float As[16][65];
    __shared__ float Bs[16][65];
    int tid = threadIdx.x;
    int bm = blockIdx.y * 64, bn = blockIdx.x * 64;
    int lk = tid & 15, lr = tid >> 4;
    int tx = tid & 15, ty = tid >> 4;
    float acc[4][4] = {};
    for (int kt = 0; kt < K; kt += 16) {
#pragma unroll
        for (int rr = 0; rr < 4; rr++) {
            int ml = lr + rr * 16;
            int m = bm + ml;
            float va = 0.f;
            if (m < M) {
                int bb = m / aBatchRows, r = m % aBatchRows;
                va = A[bb * aBatchStride + aRowOff + (long)r * K + kt + lk];
            }
            As[lk][ml] = va;
            int nl = lr + rr * 16;
            Bs[lk][nl] = W[(long)(bn + nl) * K + kt + lk];
        }
        __syncthreads();
#pragma unroll
        for (int kk = 0; kk < 16; kk++) {
            float av[4], bv[4];
#pragma unroll
            for (int i = 0; i < 4; i++) av[i] = As[kk][ty + i * 16];
#pragma unroll
            for (int j = 0; j < 4; j++) bv[j] = Bs[kk][tx + j * 16];
#pragma unroll
            for (int i = 0; i < 4; i++)
#pragma unroll
                for (int j = 0; j < 4; j++) acc[i][j] += av[i] * bv[j];
        }
        __syncthreads();
    }
#pragma unroll
    for (int i = 0; i < 4; i++) {
        int m = bm + ty + i * 16;
        if (m >= M) continue;
        const float* addrow = nullptr;
        if (Add) {
            int bb = m / addBatchRows, r = m % addBatchRows;
            addrow = Add + bb * addBatchStride + addRowOff + (long)r * N;
        }
#pragma unroll
        for (int j = 0; j < 4; j++) {
            int nn = bn + tx + j * 16;
            float v = acc[i][j] * scale;
            if (bias) v += bias[nn];
            if (reluFlag) v = fmaxf(v, 0.f);
            if (addrow) v += addrow[nn];
            Out[(long)m * N + nn] = v;
        }
    }
}

// ---------------- attention 1: P[b,h,n,q] = softmax_n( q[b,q,:]·k[b,n,:] ) (transposed store) ----
__global__ __launch_bounds__(256) void attn1_kernel(const float* __restrict__ qs,
                                                    const float* __restrict__ ks,
                                                    float* __restrict__ P) {
    int bid = blockIdx.x;
    int qi = bid % QL;
    int h = (bid / QL) % HEADS;
    int b = bid / (QL * HEADS);
    __shared__ float qrow[64];
    __shared__ float red[256];
    int tid = threadIdx.x;
    if (tid < 64) qrow[tid] = qs[((long)(b * QL + qi)) * DIM + h * 64 + tid];
    __syncthreads();
    float s = -1e30f;
    if (tid < VS) {
        const float* kr = ks + ((long)(b * VS + tid)) * DIM + h * 64;
        float acc = 0.f;
#pragma unroll 16
        for (int d = 0; d < 64; d++) acc += qrow[d] * kr[d];
        s = acc;
    }
    float m = blockReduceMax(s, red, tid);
    float e = (tid < VS) ? expf(s - m) : 0.f;
    float tot = blockReduceSum(e, red, tid);
    if (tid < VS) P[(((long)(b * HEADS + h)) * VS + tid) * QL + qi] = e / tot;
}

// ---------------- fused: h = P*v -> dwconv1+bn1+relu -> dwconv2+bn2+relu -> mean over n ----
__global__ __launch_bounds__(256) void conv_fuse_kernel(
    const float* __restrict__ P, const float* __restrict__ vs,
    const float* __restrict__ dw1, const float* __restrict__ dw2,
    const float* __restrict__ bn1g, const float* __restrict__ bn1b,
    const float* __restrict__ bn1m, const float* __restrict__ bn1v,
    const float* __restrict__ bn2g, const float* __restrict__ bn2b,
    const float* __restrict__ bn2m, const float* __restrict__ bn2v,
    float* __restrict__ m2) {
    int bc = blockIdx.x;
    int c = bc % DIM;
    int b = bc / DIM;
    int h = c >> 6;
    int tid = threadIdx.x;
    __shared__ float vcol[VS];
    __shared__ float hs[20][228];
    __shared__ float h1s[18][228];
    __shared__ float colsum[QL];
    __shared__ float w1s[9], w2s[9];
    if (tid < 9) { w1s[tid] = dw1[c * 9 + tid]; w2s[tid] = dw2[c * 9 + tid]; }
    if (tid < VS) vcol[tid] = vs[((long)(b * VS + tid)) * DIM + c];
    if (tid < QL) colsum[tid] = 0.f;
    float s1 = bn1g[c] * rsqrtf(bn1v[c] + EPS_BN);
    float b1 = bn1b[c] - bn1m[c] * s1;
    float s2 = bn2g[c] * rsqrtf(bn2v[c] + EPS_BN);
    float b2 = bn2b[c] - bn2m[c] * s2;
    const float* Pp = P + ((long)(b * HEADS + h)) * VS * QL;
    __syncthreads();
    for (int n0 = 0; n0 < VS; n0 += 16) {
        // fill h strip: rows r=0..19 <-> n = n0-2+r ; cols 0..226 <-> q = col-1
        for (int idx = tid; idx < 20 * 227; idx += 256) {
            int r = idx / 227, col = idx % 227;
            int n = n0 - 2 + r, q = col - 1;
            float val = 0.f;
            if (n >= 0 && n < VS && q >= 0 && q < QL) val = Pp[n * QL + q] * vcol[n];
            hs[r][col] = val;
        }
        __syncthreads();
        // conv1 + bn1 + relu -> h1 rows r1=0..17 <-> n1 = n0-1+r1 (zero outside valid plane!)
        for (int idx = tid; idx < 18 * 227; idx += 256) {
            int r1 = idx / 227, col = idx % 227;
            int n1 = n0 - 1 + r1, q = col - 1;
            float val = 0.f;
            if (n1 >= 0 && n1 < VS && q >= 0 && q < QL) {
                float acc = 0.f;
#pragma unroll
                for (int i = 0; i < 3; i++)
#pragma unroll
                    for (int j = 0; j < 3; j++) acc += w1s[i * 3 + j] * hs[r1 + i][col + j - 1];
                val = fmaxf(acc * s1 + b1, 0.f);
            }
            h1s[r1][col] = val;
        }
        __syncthreads();
        // conv2 + bn2 + relu -> accumulate column sums over n
        if (tid < QL) {
            int col = tid + 1;
            float acc = 0.f;
            for (int r2 = 0; r2 < 16; r2++) {
                int n2 = n0 + r2;
                if (n2 >= VS) break;
                float a = 0.f;
#pragma unroll
                for (int i = 0; i < 3; i++)
#pragma unroll
                    for (int j = 0; j < 3; j++) a += w2s[i * 3 + j] * h1s[r2 + i][col + j - 1];
                acc += fmaxf(a * s2 + b2, 0.f);
            }
            colsum[tid] += acc;
        }
        __syncthreads();
    }
    if (tid < QL) m2[((long)(b * QL + tid)) * DIM + c] = colsum[tid] * (1.f / (float)VS);
}

// ---------------- attention 2: O[b,n,:] = Qm[b,n,:] + softmax_q(Qm·Km/sqrt(512)) @ Vm ----
__global__ __launch_bounds__(256) void attn2_kernel(const float* __restrict__ Qm,
                                                    const float* __restrict__ Km,
                                                    const float* __restrict__ Vm,
                                                    float* __restrict__ O) {
    int bid = blockIdx.x;
    int n = bid % VS;
    int h = (bid / VS) % HEADS;
    int b = bid / (VS * HEADS);
    __shared__ float qrow[64];
    __shared__ float av[QL];
    __shared__ float red[256];
    int tid = threadIdx.x;
    if (tid < 64) qrow[tid] = Qm[((long)(b * VS + n)) * DIM + h * 64 + tid];
    __syncthreads();
    float s = -1e30f;
    if (tid < QL) {
        const float* kr = Km + ((long)(b * QL + tid)) * DIM + h * 64;
        float acc = 0.f;
#pragma unroll 16
        for (int d = 0; d < 64; d++) acc += qrow[d] * kr[d];
        s = acc * 0.044194173824159216f; // 1/sqrt(512)
    }
    float m = blockReduceMax(s, red, tid);
    float e = (tid < QL) ? expf(s - m) : 0.f;
    float tot = blockReduceSum(e, red, tid);
    if (tid < QL) av[tid] = e / tot;
    __syncthreads();
    int d = tid & 63, qp = tid >> 6;
    float acc = 0.f;
    for (int q = qp; q < QL; q += 4) acc += av[q] * Vm[((long)(b * QL + q)) * DIM + h * 64 + d];
    red[tid] = acc;
    __syncthreads();
    if (tid < 64) {
        float r = red[tid] + red[tid + 64] + red[tid + 128] + red[tid + 192];
        O[((long)(b * VS + n)) * DIM + h * 64 + tid] = qrow[tid] + r;
    }
}

extern "C" void kernel_launch(void* const* d_in, const int* in_sizes, int n_in,
                              void* d_out, int out_size, void* d_ws, size_t ws_size,
                              hipStream_t stream) {
    const float* x     = (const float*)d_in[0];
    const float* Wq    = (const float*)d_in[1];
    const float* Wk    = (const float*)d_in[2];
    const float* Wv    = (const float*)d_in[3];
    const float* Wproj = (const float*)d_in[4];
    const float* bproj = (const float*)d_in[5];
    const float* dw1   = (const float*)d_in[6];
    const float* dw2   = (const float*)d_in[7];
    const float* pw    = (const float*)d_in[8];
    const float* bn1g  = (const float*)d_in[9];
    const float* bn1b  = (const float*)d_in[10];
    const float* bn1m  = (const float*)d_in[11];
    const float* bn1v  = (const float*)d_in[12];
    const float* bn2g  = (const float*)d_in[13];
    const float* bn2b  = (const float*)d_in[14];
    const float* bn2m  = (const float*)d_in[15];
    const float* bn2v  = (const float*)d_in[16];
    const float* mWq   = (const float*)d_in[17];
    const float* mbq   = (const float*)d_in[18];
    const float* mWk   = (const float*)d_in[19];
    const float* mbk   = (const float*)d_in[20];
    const float* mWv   = (const float*)d_in[21];
    const float* mbv   = (const float*)d_in[22];
    const float* mWo   = (const float*)d_in[23];
    const float* mbo   = (const float*)d_in[24];

    float* ws = (float*)d_ws;
    // buffer overlay (floats):
    // S1 @ 0        : 460800  -> qs, then m2, then Km
    // S2 @ 460800   : 401408  -> ks, then O
    // S3 @ 862208   : 401408  -> vs, then O2
    // S4 @ 1263616  : 1411200 -> P, then [kc @ +0 | Qm @ +460800 | Vm @ +862208]
    float* qs = ws;
    float* ks = ws + 460800;
    float* vsb = ws + 862208;
    float* P  = ws + 1263616;
    float* m2 = ws;           // reuses qs
    float* kc = ws + 1263616; // reuses P
    float* Qm = ws + 1263616 + 460800;
    float* Vm = ws + 1263616 + 460800 + 401408;
    float* Km = ws;           // reuses m2
    float* O  = ws + 460800;  // reuses ks
    float* O2 = ws + 862208;  // reuses vs

    const long xBS = 421L * DIM;     // x batch stride
    const long clsOff = 196L * DIM;  // cls_cat row offset within batch

    dim3 blk(256);
    dim3 g900(DIM / 64, (900 + 63) / 64); // 8 x 15
    dim3 g784(DIM / 64, (784 + 63) / 64); // 8 x 13

    // 1-3: q,k,v projections (q pre-scaled by hd^-0.5 = 0.125)
    gemm_xwt<<<g900, blk, 0, stream>>>(x, QL, xBS, clsOff, Wq, nullptr,
                                       nullptr, 1, 0, 0, qs, 900, DIM, DIM, 0.125f, 0);
    gemm_xwt<<<g784, blk, 0, stream>>>(x, VS, xBS, 0, Wk, nullptr,
                                       nullptr, 1, 0, 0, ks, 784, DIM, DIM, 1.f, 0);
    gemm_xwt<<<g784, blk, 0, stream>>>(x, VS, xBS, 0, Wv, nullptr,
                                       nullptr, 1, 0, 0, vsb, 784, DIM, DIM, 1.f, 0);
    // 4: attn softmax (stored transposed: P[b,h,n,q])
    attn1_kernel<<<BATCH * HEADS * QL, blk, 0, stream>>>(qs, ks, P);
    // 5: fused outer-product + dwconv1/bn/relu + dwconv2/bn/relu + mean over n
    conv_fuse_kernel<<<BATCH * DIM, blk, 0, stream>>>(P, vsb, dw1, dw2,
                                                      bn1g, bn1b, bn1m, bn1v,
                                                      bn2g, bn2b, bn2m, bn2v, m2);
    // 6: kc = cls_cat + m2 @ pw^T   (pointwise conv commuted past mean)
    gemm_xwt<<<g900, blk, 0, stream>>>(m2, 900, 0, 0, pw, nullptr,
                                       x, QL, xBS, clsOff, kc, 900, DIM, DIM, 1.f, 0);
    // 7-9: second-stage projections
    gemm_xwt<<<g784, blk, 0, stream>>>(x, VS, xBS, 0, mWq, mbq,
                                       nullptr, 1, 0, 0, Qm, 784, DIM, DIM, 1.f, 0);
    gemm_xwt<<<g900, blk, 0, stream>>>(kc, 900, 0, 0, mWk, mbk,
                                       nullptr, 1, 0, 0, Km, 900, DIM, DIM, 1.f, 0);
    gemm_xwt<<<g900, blk, 0, stream>>>(kc, 900, 0, 0, mWv, mbv,
                                       nullptr, 1, 0, 0, Vm, 900, DIM, DIM, 1.f, 0);
    // 10: O = Qm + softmax(Qm Km^T / sqrt(512)) Vm
    attn2_kernel<<<BATCH * HEADS * VS, blk, 0, stream>>>(Qm, Km, Vm, O);
    // 11: O2 = O + relu(O @ mWo^T + mbo)
    gemm_xwt<<<g784, blk, 0, stream>>>(O, 784, 0, 0, mWo, mbo,
                                       O, 784, 0, 0, O2, 784, DIM, DIM, 1.f, 1);
    // 12: out = O2 @ Wproj^T + bproj
    gemm_xwt<<<g784, blk, 0, stream>>>(O2, 784, 0, 0, Wproj, bproj,
                                       nullptr, 1, 0, 0, (float*)d_out, 784, DIM, DIM, 1.f, 0);
}

// Round 3
// 510.916 us; speedup vs baseline: 1.8819x; 1.8819x over previous
//
#include <hip/hip_runtime.h>
#include <math.h>

#define DIM 512
#define HEADS 8
#define QL 225
#define VS 196
#define BATCH 4
#define EPS_BN 1e-5f

// ---------------- wave (64-lane) reductions ----------------
__device__ __forceinline__ float waveMax(float v) {
#pragma unroll
    for (int o = 32; o; o >>= 1) v = fmaxf(v, __shfl_xor(v, o, 64));
    return v;
}
__device__ __forceinline__ float waveSum(float v) {
#pragma unroll
    for (int o = 32; o; o >>= 1) v += __shfl_xor(v, o, 64);
    return v;
}

// ---------------- multi-job fp32 GEMM (N=K=512 fixed): Out = scale*A@W^T (+bias)(relu)(+Add) ----
struct GJob {
    const float* A; const float* W; const float* bias; const float* Add; float* Out;
    long aBS, aOff, addBS, addOff;
    int aRows, addRows, M, relu;
    float scale; int pad0, pad1, pad2;
};
struct GJobs { GJob j[4]; };

__global__ __launch_bounds__(256) void gemm_multi(GJobs jobs) {
    const GJob J = jobs.j[blockIdx.z];
    int bm = blockIdx.y * 64, bn = blockIdx.x * 64;
    if (bm >= J.M) return;
    __shared__ __align__(16) float As[16][68];
    __shared__ __align__(16) float Bs[16][68];
    int tid = threadIdx.x;
    int ml = tid >> 2, kq = (tid & 3) * 4;
    int m = bm + ml;
    bool mvalid = (m < J.M);
    const float* arow = J.A;
    if (mvalid) {
        int bb = m / J.aRows, r = m % J.aRows;
        arow = J.A + bb * J.aBS + J.aOff + (long)r * 512;
    }
    const float* wrow = J.W + (long)(bn + ml) * 512;
    int tx = tid & 15, ty = tid >> 4;
    float acc[4][4] = {};
    for (int kt = 0; kt < 512; kt += 16) {
        float4 va = make_float4(0.f, 0.f, 0.f, 0.f);
        if (mvalid) va = *reinterpret_cast<const float4*>(arow + kt + kq);
        float4 vb = *reinterpret_cast<const float4*>(wrow + kt + kq);
        As[kq + 0][ml] = va.x; As[kq + 1][ml] = va.y; As[kq + 2][ml] = va.z; As[kq + 3][ml] = va.w;
        Bs[kq + 0][ml] = vb.x; Bs[kq + 1][ml] = vb.y; Bs[kq + 2][ml] = vb.z; Bs[kq + 3][ml] = vb.w;
        __syncthreads();
#pragma unroll
        for (int kk = 0; kk < 16; kk++) {
            float4 a4 = *reinterpret_cast<const float4*>(&As[kk][ty * 4]);
            float4 b4 = *reinterpret_cast<const float4*>(&Bs[kk][tx * 4]);
            float av[4] = {a4.x, a4.y, a4.z, a4.w};
            float bv[4] = {b4.x, b4.y, b4.z, b4.w};
#pragma unroll
            for (int i = 0; i < 4; i++)
#pragma unroll
                for (int j = 0; j < 4; j++) acc[i][j] += av[i] * bv[j];
        }
        __syncthreads();
    }
#pragma unroll
    for (int i = 0; i < 4; i++) {
        int mm = bm + ty * 4 + i;
        if (mm >= J.M) continue;
        float vals[4];
        int nn0 = bn + tx * 4;
#pragma unroll
        for (int j = 0; j < 4; j++) {
            float v = acc[i][j] * J.scale;
            if (J.bias) v += J.bias[nn0 + j];
            if (J.relu) v = fmaxf(v, 0.f);
            vals[j] = v;
        }
        if (J.Add) {
            int bb = mm / J.addRows, r = mm % J.addRows;
            float4 ar = *reinterpret_cast<const float4*>(J.Add + bb * J.addBS + J.addOff + (long)r * 512 + nn0);
            vals[0] += ar.x; vals[1] += ar.y; vals[2] += ar.z; vals[3] += ar.w;
        }
        *reinterpret_cast<float4*>(J.Out + (long)mm * 512 + nn0) =
            make_float4(vals[0], vals[1], vals[2], vals[3]);
    }
}

// ---------------- attention 1: P[b,h,n,q] = softmax_n( q[b,q,:]·k[b,n,:] ) (transposed store) ----
__global__ __launch_bounds__(256) void attn1_kernel(const float* __restrict__ qs,
                                                    const float* __restrict__ ks,
                                                    float* __restrict__ P) {
    int bid = blockIdx.x;
    int qi = bid % QL;
    int h = (bid / QL) % HEADS;
    int b = bid / (QL * HEADS);
    __shared__ float qrow[64];
    __shared__ float redm[4], reds[4];
    int tid = threadIdx.x;
    if (tid < 64) qrow[tid] = qs[((long)(b * QL + qi)) * DIM + h * 64 + tid];
    __syncthreads();
    float s = -1e30f;
    if (tid < VS) {
        const float* kr = ks + ((long)(b * VS + tid)) * DIM + h * 64;
        float acc = 0.f;
#pragma unroll 16
        for (int d = 0; d < 64; d++) acc += qrow[d] * kr[d];
        s = acc;
    }
    float wm = waveMax(s);
    if ((tid & 63) == 0) redm[tid >> 6] = wm;
    __syncthreads();
    float m = fmaxf(fmaxf(redm[0], redm[1]), fmaxf(redm[2], redm[3]));
    float e = (tid < VS) ? expf(s - m) : 0.f;
    float ws = waveSum(e);
    if ((tid & 63) == 0) reds[tid >> 6] = ws;
    __syncthreads();
    float tot = reds[0] + reds[1] + reds[2] + reds[3];
    if (tid < VS) P[(((long)(b * HEADS + h)) * VS + tid) * QL + qi] = e / tot;
}

// ---------------- fused: h = P*v -> dwconv1+bn1+relu -> dwconv2+bn2+relu -> mean over n ----
// one block per (b,c) plane; one thread per padded column (227 active)
__global__ __launch_bounds__(256) void conv_fuse_kernel(
    const float* __restrict__ P, const float* __restrict__ vs,
    const float* __restrict__ dw1, const float* __restrict__ dw2,
    const float* __restrict__ bn1g, const float* __restrict__ bn1b,
    const float* __restrict__ bn1m, const float* __restrict__ bn1v,
    const float* __restrict__ bn2g, const float* __restrict__ bn2b,
    const float* __restrict__ bn2m, const float* __restrict__ bn2v,
    float* __restrict__ m2) {
    int bc = blockIdx.x;
    int c = bc & (DIM - 1);
    int b = bc >> 9;
    int h = c >> 6;
    int tid = threadIdx.x;
    __shared__ float vcol[VS];
    __shared__ float hs[20][228];
    __shared__ float h1s[18][228];
    __shared__ float w1s[9], w2s[9];
    if (tid < 9) { w1s[tid] = dw1[c * 9 + tid]; w2s[tid] = dw2[c * 9 + tid]; }
    if (tid < VS) vcol[tid] = vs[((long)(b * VS + tid)) * DIM + c];
    float s1 = bn1g[c] * rsqrtf(bn1v[c] + EPS_BN);
    float b1v = bn1b[c] - bn1m[c] * s1;
    float s2 = bn2g[c] * rsqrtf(bn2v[c] + EPS_BN);
    float b2v = bn2b[c] - bn2m[c] * s2;
    const float* Pp = P + ((long)(b * HEADS + h)) * VS * QL;
    bool colOK = (tid >= 1 && tid <= QL);
    int q = tid - 1;
    float csum = 0.f;
    __syncthreads();
    for (int n0 = 0; n0 < VS; n0 += 16) {
        // fill hs rows 0..19  <->  n = n0-2+r (zero outside plane / halo cols)
        if (tid < 227) {
#pragma unroll
            for (int r = 0; r < 20; r++) {
                int n = n0 - 2 + r;
                float val = 0.f;
                if (colOK && n >= 0 && n < VS) val = Pp[n * QL + q] * vcol[n];
                hs[r][tid] = val;
            }
        }
        __syncthreads();
        // conv1 + bn1 + relu -> h1s rows 0..17 <-> n1 = n0-1+r1 (zero outside plane)
        if (tid < 227) {
            float a0 = 0.f, a1 = 0.f, a2 = 0.f, e0 = 0.f, e1 = 0.f, e2 = 0.f;
            if (colOK) {
                a0 = hs[0][tid - 1]; a1 = hs[0][tid]; a2 = hs[0][tid + 1];
                e0 = hs[1][tid - 1]; e1 = hs[1][tid]; e2 = hs[1][tid + 1];
            }
#pragma unroll
            for (int r1 = 0; r1 < 18; r1++) {
                float c0 = 0.f, c1 = 0.f, c2 = 0.f;
                if (colOK) {
                    c0 = hs[r1 + 2][tid - 1]; c1 = hs[r1 + 2][tid]; c2 = hs[r1 + 2][tid + 1];
                }
                int n1 = n0 - 1 + r1;
                float val = 0.f;
                if (colOK && n1 >= 0 && n1 < VS) {
                    float acc = w1s[0] * a0 + w1s[1] * a1 + w1s[2] * a2
                              + w1s[3] * e0 + w1s[4] * e1 + w1s[5] * e2
                              + w1s[6] * c0 + w1s[7] * c1 + w1s[8] * c2;
                    val = fmaxf(acc * s1 + b1v, 0.f);
                }
                h1s[r1][tid] = val;
                a0 = e0; a1 = e1; a2 = e2;
                e0 = c0; e1 = c1; e2 = c2;
            }
        }
        __syncthreads();
        // conv2 + bn2 + relu -> accumulate per-column sum in register
        if (colOK) {
            float a0 = h1s[0][tid - 1], a1 = h1s[0][tid], a2 = h1s[0][tid + 1];
            float e0 = h1s[1][tid - 1], e1 = h1s[1][tid], e2 = h1s[1][tid + 1];
#pragma unroll
            for (int r2 = 0; r2 < 16; r2++) {
                float c0 = h1s[r2 + 2][tid - 1], c1 = h1s[r2 + 2][tid], c2 = h1s[r2 + 2][tid + 1];
                if (n0 + r2 < VS) {
                    float acc2 = w2s[0] * a0 + w2s[1] * a1 + w2s[2] * a2
                               + w2s[3] * e0 + w2s[4] * e1 + w2s[5] * e2
                               + w2s[6] * c0 + w2s[7] * c1 + w2s[8] * c2;
                    csum += fmaxf(acc2 * s2 + b2v, 0.f);
                }
                a0 = e0; a1 = e1; a2 = e2;
                e0 = c0; e1 = c1; e2 = c2;
            }
        }
        __syncthreads();  // h1s/hs reuse barrier for next strip
    }
    if (colOK) m2[((long)(b * QL + q)) * DIM + c] = csum * (1.f / (float)VS);
}

// ---------------- attention 2: O[b,n,:] = Qm[b,n,:] + softmax_q(Qm·Km/sqrt(512)) @ Vm ----
__global__ __launch_bounds__(256) void attn2_kernel(const float* __restrict__ Qm,
                                                    const float* __restrict__ Km,
                                                    const float* __restrict__ Vm,
                                                    float* __restrict__ O) {
    int bid = blockIdx.x;
    int n = bid % VS;
    int h = (bid / VS) % HEADS;
    int b = bid / (VS * HEADS);
    __shared__ float qrow[64];
    __shared__ float av[QL];
    __shared__ float red[256];
    __shared__ float redm[4], reds[4];
    int tid = threadIdx.x;
    if (tid < 64) qrow[tid] = Qm[((long)(b * VS + n)) * DIM + h * 64 + tid];
    __syncthreads();
    float s = -1e30f;
    if (tid < QL) {
        const float* kr = Km + ((long)(b * QL + tid)) * DIM + h * 64;
        float acc = 0.f;
#pragma unroll 16
        for (int d = 0; d < 64; d++) acc += qrow[d] * kr[d];
        s = acc * 0.044194173824159216f; // 1/sqrt(512)
    }
    float wm = waveMax(s);
    if ((tid & 63) == 0) redm[tid >> 6] = wm;
    __syncthreads();
    float m = fmaxf(fmaxf(redm[0], redm[1]), fmaxf(redm[2], redm[3]));
    float e = (tid < QL) ? expf(s - m) : 0.f;
    float ws = waveSum(e);
    if ((tid & 63) == 0) reds[tid >> 6] = ws;
    __syncthreads();
    float tot = reds[0] + reds[1] + reds[2] + reds[3];
    if (tid < QL) av[tid] = e / tot;
    __syncthreads();
    int d = tid & 63, qp = tid >> 6;
    float acc = 0.f;
    for (int qq = qp; qq < QL; qq += 4) acc += av[qq] * Vm[((long)(b * QL + qq)) * DIM + h * 64 + d];
    red[tid] = acc;
    __syncthreads();
    if (tid < 64) {
        float r = red[tid] + red[tid + 64] + red[tid + 128] + red[tid + 192];
        O[((long)(b * VS + n)) * DIM + h * 64 + tid] = qrow[tid] + r;
    }
}

static inline GJob mkjob(const float* A, int aRows, long aBS, long aOff,
                         const float* W, const float* bias,
                         const float* Add, int addRows, long addBS, long addOff,
                         float* Out, int M, float scale, int relu) {
    GJob j;
    j.A = A; j.W = W; j.bias = bias; j.Add = Add; j.Out = Out;
    j.aBS = aBS; j.aOff = aOff; j.addBS = addBS; j.addOff = addOff;
    j.aRows = aRows; j.addRows = addRows; j.M = M; j.relu = relu;
    j.scale = scale; j.pad0 = j.pad1 = j.pad2 = 0;
    return j;
}

extern "C" void kernel_launch(void* const* d_in, const int* in_sizes, int n_in,
                              void* d_out, int out_size, void* d_ws, size_t ws_size,
                              hipStream_t stream) {
    const float* x     = (const float*)d_in[0];
    const float* Wq    = (const float*)d_in[1];
    const float* Wk    = (const float*)d_in[2];
    const float* Wv    = (const float*)d_in[3];
    const float* Wproj = (const float*)d_in[4];
    const float* bproj = (const float*)d_in[5];
    const float* dw1   = (const float*)d_in[6];
    const float* dw2   = (const float*)d_in[7];
    const float* pw    = (const float*)d_in[8];
    const float* bn1g  = (const float*)d_in[9];
    const float* bn1b  = (const float*)d_in[10];
    const float* bn1m  = (const float*)d_in[11];
    const float* bn1v  = (const float*)d_in[12];
    const float* bn2g  = (const float*)d_in[13];
    const float* bn2b  = (const float*)d_in[14];
    const float* bn2m  = (const float*)d_in[15];
    const float* bn2v  = (const float*)d_in[16];
    const float* mWq   = (const float*)d_in[17];
    const float* mbq   = (const float*)d_in[18];
    const float* mWk   = (const float*)d_in[19];
    const float* mbk   = (const float*)d_in[20];
    const float* mWv   = (const float*)d_in[21];
    const float* mbv   = (const float*)d_in[22];
    const float* mWo   = (const float*)d_in[23];
    const float* mbo   = (const float*)d_in[24];

    float* ws = (float*)d_ws;
    // Round-1 proven overlay (floats):
    //   qs @ 0 (460800) -> m2 -> Km
    //   ks @ 460800 (401408) -> O
    //   vsb @ 862208 (401408) -> O2
    //   P @ 1263616 (1411200) -> [kc @ +0 (460800) | Qm @ +460800 (401408) | Vm @ +862208 (460800)]
    // Qm/Vm/kc are only written AFTER conv_fuse has consumed P.
    float* qs = ws;
    float* ks = ws + 460800;
    float* vsb = ws + 862208;
    float* P  = ws + 1263616;
    float* m2 = ws;           // reuses qs
    float* kc = ws + 1263616; // reuses P
    float* Qm = ws + 1263616 + 460800;
    float* Vm = ws + 1263616 + 460800 + 401408;
    float* Km = ws;           // reuses m2
    float* O  = ws + 460800;  // reuses ks
    float* O2 = ws + 862208;  // reuses vsb

    const long xBS = 421L * DIM;
    const long clsOff = 196L * DIM;

    dim3 blk(256);

    // L1: q,k,v projections fused (360 blocks)
    {
        GJobs js;
        js.j[0] = mkjob(x, QL, xBS, clsOff, Wq, nullptr, nullptr, 1, 0, 0, qs, 900, 0.125f, 0);
        js.j[1] = mkjob(x, VS, xBS, 0, Wk, nullptr, nullptr, 1, 0, 0, ks, 784, 1.f, 0);
        js.j[2] = mkjob(x, VS, xBS, 0, Wv, nullptr, nullptr, 1, 0, 0, vsb, 784, 1.f, 0);
        js.j[3] = js.j[0];
        gemm_multi<<<dim3(8, 15, 3), blk, 0, stream>>>(js);
    }
    attn1_kernel<<<BATCH * HEADS * QL, blk, 0, stream>>>(qs, ks, P);
    conv_fuse_kernel<<<BATCH * DIM, blk, 0, stream>>>(P, vsb, dw1, dw2,
                                                      bn1g, bn1b, bn1m, bn1v,
                                                      bn2g, bn2b, bn2m, bn2v, m2);
    // L2: kc = cls_cat + m2 @ pw^T  AND  Qm = x_sem @ mWq^T + mbq   (P dead now)
    {
        GJobs js;
        js.j[0] = mkjob(m2, 900, 0, 0, pw, nullptr, x, QL, xBS, clsOff, kc, 900, 1.f, 0);
        js.j[1] = mkjob(x, VS, xBS, 0, mWq, mbq, nullptr, 1, 0, 0, Qm, 784, 1.f, 0);
        js.j[2] = js.j[3] = js.j[0];
        gemm_multi<<<dim3(8, 15, 2), blk, 0, stream>>>(js);
    }
    // L3: Km, Vm off kc (240 blocks)
    {
        GJobs js;
        js.j[0] = mkjob(kc, 900, 0, 0, mWk, mbk, nullptr, 1, 0, 0, Km, 900, 1.f, 0);
        js.j[1] = mkjob(kc, 900, 0, 0, mWv, mbv, nullptr, 1, 0, 0, Vm, 900, 1.f, 0);
        js.j[2] = js.j[3] = js.j[0];
        gemm_multi<<<dim3(8, 15, 2), blk, 0, stream>>>(js);
    }
    attn2_kernel<<<BATCH * HEADS * VS, blk, 0, stream>>>(Qm, Km, Vm, O);
    // L4: O2 = O + relu(O @ mWo^T + mbo)
    {
        GJobs js;
        js.j[0] = mkjob(O, 784, 0, 0, mWo, mbo, O, 784, 0, 0, O2, 784, 1.f, 1);
        js.j[1] = js.j[2] = js.j[3] = js.j[0];
        gemm_multi<<<dim3(8, 13, 1), blk, 0, stream>>>(js);
    }
    // L5: out = O2 @ Wproj^T + bproj
    {
        GJobs js;
        js.j[0] = mkjob(O2, 784, 0, 0, Wproj, bproj, nullptr, 1, 0, 0, (float*)d_out, 784, 1.f, 0);
        js.j[1] = js.j[2] = js.j[3] = js.j[0];
        gemm_multi<<<dim3(8, 13, 1), blk, 0, stream>>>(js);
    }
}

// Round 4
// 411.209 us; speedup vs baseline: 2.3382x; 1.2425x over previous
//
#include <hip/hip_runtime.h>
#include <math.h>

#define DIM 512
#define HEADS 8
#define QL 225
#define VS 196
#define BATCH 4
#define EPS_BN 1e-5f

// ---------------- wave (64-lane) reductions ----------------
__device__ __forceinline__ float waveMax(float v) {
#pragma unroll
    for (int o = 32; o; o >>= 1) v = fmaxf(v, __shfl_xor(v, o, 64));
    return v;
}
__device__ __forceinline__ float waveSum(float v) {
#pragma unroll
    for (int o = 32; o; o >>= 1) v += __shfl_xor(v, o, 64);
    return v;
}

// ---------------- multi-job fp32 GEMM (N=K=512 fixed): Out = scale*A@W^T (+bias)(relu)(+Add) ----
struct GJob {
    const float* A; const float* W; const float* bias; const float* Add; float* Out;
    long aBS, aOff, addBS, addOff;
    int aRows, addRows, M, relu;
    float scale; int pad0, pad1, pad2;
};
struct GJobs { GJob j[4]; };

__global__ __launch_bounds__(256) void gemm_multi(GJobs jobs) {
    const GJob J = jobs.j[blockIdx.z];
    int bm = blockIdx.y * 64, bn = blockIdx.x * 64;
    if (bm >= J.M) return;
    __shared__ __align__(16) float As[16][68];
    __shared__ __align__(16) float Bs[16][68];
    int tid = threadIdx.x;
    int ml = tid >> 2, kq = (tid & 3) * 4;
    int m = bm + ml;
    bool mvalid = (m < J.M);
    const float* arow = J.A;
    if (mvalid) {
        int bb = m / J.aRows, r = m % J.aRows;
        arow = J.A + bb * J.aBS + J.aOff + (long)r * 512;
    }
    const float* wrow = J.W + (long)(bn + ml) * 512;
    int tx = tid & 15, ty = tid >> 4;
    float acc[4][4] = {};
    for (int kt = 0; kt < 512; kt += 16) {
        float4 va = make_float4(0.f, 0.f, 0.f, 0.f);
        if (mvalid) va = *reinterpret_cast<const float4*>(arow + kt + kq);
        float4 vb = *reinterpret_cast<const float4*>(wrow + kt + kq);
        As[kq + 0][ml] = va.x; As[kq + 1][ml] = va.y; As[kq + 2][ml] = va.z; As[kq + 3][ml] = va.w;
        Bs[kq + 0][ml] = vb.x; Bs[kq + 1][ml] = vb.y; Bs[kq + 2][ml] = vb.z; Bs[kq + 3][ml] = vb.w;
        __syncthreads();
#pragma unroll
        for (int kk = 0; kk < 16; kk++) {
            float4 a4 = *reinterpret_cast<const float4*>(&As[kk][ty * 4]);
            float4 b4 = *reinterpret_cast<const float4*>(&Bs[kk][tx * 4]);
            float av[4] = {a4.x, a4.y, a4.z, a4.w};
            float bv[4] = {b4.x, b4.y, b4.z, b4.w};
#pragma unroll
            for (int i = 0; i < 4; i++)
#pragma unroll
                for (int j = 0; j < 4; j++) acc[i][j] += av[i] * bv[j];
        }
        __syncthreads();
    }
#pragma unroll
    for (int i = 0; i < 4; i++) {
        int mm = bm + ty * 4 + i;
        if (mm >= J.M) continue;
        float vals[4];
        int nn0 = bn + tx * 4;
#pragma unroll
        for (int j = 0; j < 4; j++) {
            float v = acc[i][j] * J.scale;
            if (J.bias) v += J.bias[nn0 + j];
            if (J.relu) v = fmaxf(v, 0.f);
            vals[j] = v;
        }
        if (J.Add) {
            int bb = mm / J.addRows, r = mm % J.addRows;
            float4 ar = *reinterpret_cast<const float4*>(J.Add + bb * J.addBS + J.addOff + (long)r * 512 + nn0);
            vals[0] += ar.x; vals[1] += ar.y; vals[2] += ar.z; vals[3] += ar.w;
        }
        *reinterpret_cast<float4*>(J.Out + (long)mm * 512 + nn0) =
            make_float4(vals[0], vals[1], vals[2], vals[3]);
    }
}

// ---------------- attention 1: P[b,h,n,q] = softmax_n( q[b,q,:]·k[b,n,:] ) (transposed store) ----
__global__ __launch_bounds__(256) void attn1_kernel(const float* __restrict__ qs,
                                                    const float* __restrict__ ks,
                                                    float* __restrict__ P) {
    int bid = blockIdx.x;
    int qi = bid % QL;
    int h = (bid / QL) % HEADS;
    int b = bid / (QL * HEADS);
    __shared__ float qrow[64];
    __shared__ float redm[4], reds[4];
    int tid = threadIdx.x;
    if (tid < 64) qrow[tid] = qs[((long)(b * QL + qi)) * DIM + h * 64 + tid];
    __syncthreads();
    float s = -1e30f;
    if (tid < VS) {
        const float* kr = ks + ((long)(b * VS + tid)) * DIM + h * 64;
        float acc = 0.f;
#pragma unroll 16
        for (int d = 0; d < 64; d++) acc += qrow[d] * kr[d];
        s = acc;
    }
    float wm = waveMax(s);
    if ((tid & 63) == 0) redm[tid >> 6] = wm;
    __syncthreads();
    float m = fmaxf(fmaxf(redm[0], redm[1]), fmaxf(redm[2], redm[3]));
    float e = (tid < VS) ? expf(s - m) : 0.f;
    float ws = waveSum(e);
    if ((tid & 63) == 0) reds[tid >> 6] = ws;
    __syncthreads();
    float tot = reds[0] + reds[1] + reds[2] + reds[3];
    if (tid < VS) P[(((long)(b * HEADS + h)) * VS + tid) * QL + qi] = e / tot;
}

// ---------------- fused: h = P*v -> dwconv1+bn1+relu -> dwconv2+bn2+relu -> mean over n ----
// Register-streaming version: one block per (b,c) plane, 4 waves.
// Wave w owns output columns [w*60, w*60+59]; lane -> q = w*60 + lane - 2
// (lanes 0,1,62,63 are halo). Rolling 3-row register windows, shfl for
// horizontal taps. No LDS tiles, no barriers in the main loop.
#define CSTEP(N, HAm,HAc,HAp, HBm,HBc,HBp, HCm,HCc,HCp, GAm,GAc,GAp, GBm,GBc,GBp, GCm,GCc,GCp) \
{                                                                                             \
    float pv = 0.f;                                                                           \
    if ((N) < VS) {                                                                           \
        float vn = vcol[(N)];                                                                 \
        if (qload) pv = Pp[(long)(N) * QL + q] * vn;                                          \
    }                                                                                         \
    HCc = pv;                                                                                 \
    HCm = __shfl_up(pv, 1, 64);                                                               \
    HCp = __shfl_down(pv, 1, 64);                                                             \
    float g = 0.f;                                                                            \
    if (gok && (N) >= 1 && (N) <= VS) {                                                       \
        float a1 = w1s[0]*HAm + w1s[1]*HAc + w1s[2]*HAp                                       \
                 + w1s[3]*HBm + w1s[4]*HBc + w1s[5]*HBp                                       \
                 + w1s[6]*HCm + w1s[7]*HCc + w1s[8]*HCp;                                      \
        g = fmaxf(a1 * s1 + b1v, 0.f);                                                        \
    }                                                                                         \
    GCc = g;                                                                                  \
    GCm = __shfl_up(g, 1, 64);                                                                \
    GCp = __shfl_down(g, 1, 64);                                                              \
    if ((N) >= 2) {                                                                           \
        float a2 = w2s[0]*GAm + w2s[1]*GAc + w2s[2]*GAp                                       \
                 + w2s[3]*GBm + w2s[4]*GBc + w2s[5]*GBp                                       \
                 + w2s[6]*GCm + w2s[7]*GCc + w2s[8]*GCp;                                      \
        csum += fmaxf(a2 * s2 + b2v, 0.f);                                                    \
    }                                                                                         \
}

__global__ __launch_bounds__(256) void conv_fuse_kernel(
    const float* __restrict__ P, const float* __restrict__ vs,
    const float* __restrict__ dw1, const float* __restrict__ dw2,
    const float* __restrict__ bn1g, const float* __restrict__ bn1b,
    const float* __restrict__ bn1m, const float* __restrict__ bn1v,
    const float* __restrict__ bn2g, const float* __restrict__ bn2b,
    const float* __restrict__ bn2m, const float* __restrict__ bn2v,
    float* __restrict__ m2) {
    int bc = blockIdx.x;
    int c = bc & (DIM - 1);
    int b = bc >> 9;
    int h = c >> 6;
    int tid = threadIdx.x;
    int wave = tid >> 6, lane = tid & 63;
    int q = wave * 60 + lane - 2;                  // column this lane tracks
    bool qload = (q >= 0 && q < QL);               // h (=P*v) valid here
    bool gok = (lane >= 1 && lane <= 62 && q >= 0 && q < QL);  // h1 computable
    bool outok = (lane >= 2 && lane <= 61 && q < QL);          // h2/output owner
    __shared__ float vcol[VS];
    if (tid < VS) vcol[tid] = vs[((long)(b * VS + tid)) * DIM + c];
    float w1s[9], w2s[9];
#pragma unroll
    for (int i = 0; i < 9; i++) { w1s[i] = dw1[c * 9 + i]; w2s[i] = dw2[c * 9 + i]; }
    float s1 = bn1g[c] * rsqrtf(bn1v[c] + EPS_BN);
    float b1v = bn1b[c] - bn1m[c] * s1;
    float s2 = bn2g[c] * rsqrtf(bn2v[c] + EPS_BN);
    float b2v = bn2b[c] - bn2m[c] * s2;
    const float* Pp = P + ((long)(b * HEADS + h)) * VS * QL;
    __syncthreads();
    float HAm = 0, HAc = 0, HAp = 0, HBm = 0, HBc = 0, HBp = 0, HCm = 0, HCc = 0, HCp = 0;
    float GAm = 0, GAc = 0, GAp = 0, GBm = 0, GBc = 0, GBp = 0, GCm = 0, GCc = 0, GCp = 0;
    float csum = 0.f;
    // stream n = 0..197 (198 = 3*66 steps), cyclic register rotation
    for (int nb = 0; nb < 198; nb += 3) {
        CSTEP(nb,     HAm,HAc,HAp, HBm,HBc,HBp, HCm,HCc,HCp, GAm,GAc,GAp, GBm,GBc,GBp, GCm,GCc,GCp)
        CSTEP(nb + 1, HBm,HBc,HBp, HCm,HCc,HCp, HAm,HAc,HAp, GBm,GBc,GBp, GCm,GCc,GCp, GAm,GAc,GAp)
        CSTEP(nb + 2, HCm,HCc,HCp, HAm,HAc,HAp, HBm,HBc,HBp, GCm,GCc,GCp, GAm,GAc,GAp, GBm,GBc,GBp)
    }
    if (outok) m2[((long)(b * QL + q)) * DIM + c] = csum * (1.f / (float)VS);
}

// ---------------- attention 2: O[b,n,:] = Qm[b,n,:] + softmax_q(Qm·Km/sqrt(512)) @ Vm ----
__global__ __launch_bounds__(256) void attn2_kernel(const float* __restrict__ Qm,
                                                    const float* __restrict__ Km,
                                                    const float* __restrict__ Vm,
                                                    float* __restrict__ O) {
    int bid = blockIdx.x;
    int n = bid % VS;
    int h = (bid / VS) % HEADS;
    int b = bid / (VS * HEADS);
    __shared__ float qrow[64];
    __shared__ float av[QL];
    __shared__ float red[256];
    __shared__ float redm[4], reds[4];
    int tid = threadIdx.x;
    if (tid < 64) qrow[tid] = Qm[((long)(b * VS + n)) * DIM + h * 64 + tid];
    __syncthreads();
    float s = -1e30f;
    if (tid < QL) {
        const float* kr = Km + ((long)(b * QL + tid)) * DIM + h * 64;
        float acc = 0.f;
#pragma unroll 16
        for (int d = 0; d < 64; d++) acc += qrow[d] * kr[d];
        s = acc * 0.044194173824159216f; // 1/sqrt(512)
    }
    float wm = waveMax(s);
    if ((tid & 63) == 0) redm[tid >> 6] = wm;
    __syncthreads();
    float m = fmaxf(fmaxf(redm[0], redm[1]), fmaxf(redm[2], redm[3]));
    float e = (tid < QL) ? expf(s - m) : 0.f;
    float ws = waveSum(e);
    if ((tid & 63) == 0) reds[tid >> 6] = ws;
    __syncthreads();
    float tot = reds[0] + reds[1] + reds[2] + reds[3];
    if (tid < QL) av[tid] = e / tot;
    __syncthreads();
    int d = tid & 63, qp = tid >> 6;
    float acc = 0.f;
    for (int qq = qp; qq < QL; qq += 4) acc += av[qq] * Vm[((long)(b * QL + qq)) * DIM + h * 64 + d];
    red[tid] = acc;
    __syncthreads();
    if (tid < 64) {
        float r = red[tid] + red[tid + 64] + red[tid + 128] + red[tid + 192];
        O[((long)(b * VS + n)) * DIM + h * 64 + tid] = qrow[tid] + r;
    }
}

static inline GJob mkjob(const float* A, int aRows, long aBS, long aOff,
                         const float* W, const float* bias,
                         const float* Add, int addRows, long addBS, long addOff,
                         float* Out, int M, float scale, int relu) {
    GJob j;
    j.A = A; j.W = W; j.bias = bias; j.Add = Add; j.Out = Out;
    j.aBS = aBS; j.aOff = aOff; j.addBS = addBS; j.addOff = addOff;
    j.aRows = aRows; j.addRows = addRows; j.M = M; j.relu = relu;
    j.scale = scale; j.pad0 = j.pad1 = j.pad2 = 0;
    return j;
}

extern "C" void kernel_launch(void* const* d_in, const int* in_sizes, int n_in,
                              void* d_out, int out_size, void* d_ws, size_t ws_size,
                              hipStream_t stream) {
    const float* x     = (const float*)d_in[0];
    const float* Wq    = (const float*)d_in[1];
    const float* Wk    = (const float*)d_in[2];
    const float* Wv    = (const float*)d_in[3];
    const float* Wproj = (const float*)d_in[4];
    const float* bproj = (const float*)d_in[5];
    const float* dw1   = (const float*)d_in[6];
    const float* dw2   = (const float*)d_in[7];
    const float* pw    = (const float*)d_in[8];
    const float* bn1g  = (const float*)d_in[9];
    const float* bn1b  = (const float*)d_in[10];
    const float* bn1m  = (const float*)d_in[11];
    const float* bn1v  = (const float*)d_in[12];
    const float* bn2g  = (const float*)d_in[13];
    const float* bn2b  = (const float*)d_in[14];
    const float* bn2m  = (const float*)d_in[15];
    const float* bn2v  = (const float*)d_in[16];
    const float* mWq   = (const float*)d_in[17];
    const float* mbq   = (const float*)d_in[18];
    const float* mWk   = (const float*)d_in[19];
    const float* mbk   = (const float*)d_in[20];
    const float* mWv   = (const float*)d_in[21];
    const float* mbv   = (const float*)d_in[22];
    const float* mWo   = (const float*)d_in[23];
    const float* mbo   = (const float*)d_in[24];

    float* ws = (float*)d_ws;
    // Overlay (floats):
    //   qs @ 0 (460800) -> m2 -> Km
    //   ks @ 460800 (401408) -> O
    //   vsb @ 862208 (401408) -> O2
    //   P @ 1263616 (1411200) -> [kc @ +0 | Qm @ +460800 | Vm @ +862208]
    float* qs = ws;
    float* ks = ws + 460800;
    float* vsb = ws + 862208;
    float* P  = ws + 1263616;
    float* m2 = ws;
    float* kc = ws + 1263616;
    float* Qm = ws + 1263616 + 460800;
    float* Vm = ws + 1263616 + 460800 + 401408;
    float* Km = ws;
    float* O  = ws + 460800;
    float* O2 = ws + 862208;

    const long xBS = 421L * DIM;
    const long clsOff = 196L * DIM;

    dim3 blk(256);

    // L1: q,k,v projections fused (360 blocks)
    {
        GJobs js;
        js.j[0] = mkjob(x, QL, xBS, clsOff, Wq, nullptr, nullptr, 1, 0, 0, qs, 900, 0.125f, 0);
        js.j[1] = mkjob(x, VS, xBS, 0, Wk, nullptr, nullptr, 1, 0, 0, ks, 784, 1.f, 0);
        js.j[2] = mkjob(x, VS, xBS, 0, Wv, nullptr, nullptr, 1, 0, 0, vsb, 784, 1.f, 0);
        js.j[3] = js.j[0];
        gemm_multi<<<dim3(8, 15, 3), blk, 0, stream>>>(js);
    }
    attn1_kernel<<<BATCH * HEADS * QL, blk, 0, stream>>>(qs, ks, P);
    conv_fuse_kernel<<<BATCH * DIM, blk, 0, stream>>>(P, vsb, dw1, dw2,
                                                      bn1g, bn1b, bn1m, bn1v,
                                                      bn2g, bn2b, bn2m, bn2v, m2);
    // L2: kc = cls_cat + m2 @ pw^T  AND  Qm = x_sem @ mWq^T + mbq   (P dead now)
    {
        GJobs js;
        js.j[0] = mkjob(m2, 900, 0, 0, pw, nullptr, x, QL, xBS, clsOff, kc, 900, 1.f, 0);
        js.j[1] = mkjob(x, VS, xBS, 0, mWq, mbq, nullptr, 1, 0, 0, Qm, 784, 1.f, 0);
        js.j[2] = js.j[3] = js.j[0];
        gemm_multi<<<dim3(8, 15, 2), blk, 0, stream>>>(js);
    }
    // L3: Km, Vm off kc (240 blocks)
    {
        GJobs js;
        js.j[0] = mkjob(kc, 900, 0, 0, mWk, mbk, nullptr, 1, 0, 0, Km, 900, 1.f, 0);
        js.j[1] = mkjob(kc, 900, 0, 0, mWv, mbv, nullptr, 1, 0, 0, Vm, 900, 1.f, 0);
        js.j[2] = js.j[3] = js.j[0];
        gemm_multi<<<dim3(8, 15, 2), blk, 0, stream>>>(js);
    }
    attn2_kernel<<<BATCH * HEADS * VS, blk, 0, stream>>>(Qm, Km, Vm, O);
    // L4: O2 = O + relu(O @ mWo^T + mbo)
    {
        GJobs js;
        js.j[0] = mkjob(O, 784, 0, 0, mWo, mbo, O, 784, 0, 0, O2, 784, 1.f, 1);
        js.j[1] = js.j[2] = js.j[3] = js.j[0];
        gemm_multi<<<dim3(8, 13, 1), blk, 0, stream>>>(js);
    }
    // L5: out = O2 @ Wproj^T + bproj
    {
        GJobs js;
        js.j[0] = mkjob(O2, 784, 0, 0, Wproj, bproj, nullptr, 1, 0, 0, (float*)d_out, 784, 1.f, 0);
        js.j[1] = js.j[2] = js.j[3] = js.j[0];
        gemm_multi<<<dim3(8, 13, 1), blk, 0, stream>>>(js);
    }
}